// Round 22
// baseline (357.972 us; speedup 1.0000x reference)
//
#include <hip/hip_runtime.h>
#include <hip/hip_bf16.h>

// S=512, M=512, B=8, NH=16, HD=64, H=1024, K=1024, LAYERS=2, TOTAL_LEN=1536
#define OUT_OFF 4194304      // B*S*H floats (part-1 of d_out)
#define NM_ELEMS 25165824    // 2*8*1536*1024 floats (part-2: new_mem)

typedef __attribute__((ext_vector_type(8))) short short8;
typedef __attribute__((ext_vector_type(4))) float f32x4;

static __device__ __forceinline__ float4 ld4(const float* p) {
  return *reinterpret_cast<const float4*>(p);
}
static __device__ __forceinline__ void st4(float* p, float4 v) {
  *reinterpret_cast<float4*>(p) = v;
}
// non-temporal 16B copy ops (nt cache policy)
static __device__ __forceinline__ f32x4 ldnt(const float* p) {
  return __builtin_nontemporal_load(reinterpret_cast<const f32x4*>(p));
}
static __device__ __forceinline__ void stnt(float* p, f32x4 v) {
  __builtin_nontemporal_store(v, reinterpret_cast<f32x4*>(p));
}
static __device__ __forceinline__ short bfbits(float f) {
  __hip_bfloat16 h = __float2bfloat16(f);
  return *reinterpret_cast<short*>(&h);
}
// async global->LDS, 16B per lane; lds base must be wave-uniform.
static __device__ __forceinline__ void gload16(const void* g, void* l) {
  __builtin_amdgcn_global_load_lds(
      (const __attribute__((address_space(1))) void*)g,
      (__attribute__((address_space(3))) void*)l, 16, 0, 0);
}
// Barrier ordering LDS only (lgkm); keeps VMEM prefetches in flight.
static __device__ __forceinline__ void barrier_nodrain() {
  asm volatile("s_waitcnt lgkmcnt(0)" ::: "memory");
  __builtin_amdgcn_sched_barrier(0);
  __builtin_amdgcn_s_barrier();
  __builtin_amdgcn_sched_barrier(0);
}

// ---------------------------------------------------------------------------
// Pre-pass 1: weight transpose+convert. Wt[n][k] = bf16(W[k][n]), 1024x1024.
// ---------------------------------------------------------------------------
__global__ __launch_bounds__(256)
void cw_k(const float* __restrict__ W0, const float* __restrict__ W1,
          const float* __restrict__ W2, const float* __restrict__ W3,
          const float* __restrict__ W4,
          __hip_bfloat16* __restrict__ T0, __hip_bfloat16* __restrict__ T1,
          __hip_bfloat16* __restrict__ T2, __hip_bfloat16* __restrict__ T3,
          __hip_bfloat16* __restrict__ T4)
{
  const float* W; __hip_bfloat16* T;
  switch (blockIdx.z) {
    case 0: W = W0; T = T0; break;
    case 1: W = W1; T = T1; break;
    case 2: W = W2; T = T2; break;
    case 3: W = W3; T = T3; break;
    default: W = W4; T = T4; break;
  }
  __shared__ short S[64][72];
  const int t = threadIdx.x;
  const int n0 = blockIdx.x * 64, k0 = blockIdx.y * 64;
  #pragma unroll
  for (int it = 0; it < 2; ++it) {
    const int kl = (t >> 3) + it * 32;
    const int n8 = (t & 7) * 8;
    const float* src = W + (size_t)(k0 + kl) * 1024 + n0 + n8;
    const float4 f0 = ld4(src), f1 = ld4(src + 4);
    short8 s;
    s[0]=bfbits(f0.x); s[1]=bfbits(f0.y); s[2]=bfbits(f0.z); s[3]=bfbits(f0.w);
    s[4]=bfbits(f1.x); s[5]=bfbits(f1.y); s[6]=bfbits(f1.z); s[7]=bfbits(f1.w);
    *reinterpret_cast<short8*>(&S[kl][n8]) = s;
  }
  __syncthreads();
  #pragma unroll
  for (int it = 0; it < 2; ++it) {
    const int nl = (t >> 3) + it * 32;
    const int k8 = (t & 7) * 8;
    short8 s;
    #pragma unroll
    for (int e = 0; e < 8; ++e) s[e] = S[k8 + e][nl];
    *reinterpret_cast<short8*>((short*)T + (size_t)(n0 + nl) * 1024 + k0 + k8) = s;
  }
}

// ---------------------------------------------------------------------------
// Pre-pass 2: Kvx[r][k] bf16, r = b*1024 + j gathered from mem slice / x.
// ---------------------------------------------------------------------------
__global__ __launch_bounds__(256)
void ckvx_k(const float* __restrict__ x, const float* __restrict__ mem,
            const int* __restrict__ lp, const int* __restrict__ sp,
            __hip_bfloat16* __restrict__ Kvx)
{
  const size_t t = (size_t)blockIdx.x * 256 + threadIdx.x;
  const int r = (int)(t >> 7);
  const int c = (int)(t & 127) * 8;
  const int b = r >> 10, j = r & 1023;
  const float* src = (j < 512)
    ? mem + (((size_t)lp[0] * 8 + b) * 1536 + (size_t)sp[0] * 512 + j) * 1024 + c
    : x + ((size_t)b * 512 + (j - 512)) * 1024 + c;
  const float4 f0 = ld4(src), f1 = ld4(src + 4);
  short8 s;
  s[0]=bfbits(f0.x); s[1]=bfbits(f0.y); s[2]=bfbits(f0.z); s[3]=bfbits(f0.w);
  s[4]=bfbits(f1.x); s[5]=bfbits(f1.y); s[6]=bfbits(f1.z); s[7]=bfbits(f1.w);
  *reinterpret_cast<short8*>((short*)Kvx + (size_t)r * 1024 + c) = s;
}

// Pre-pass 3: rpe fp32 -> bf16 elementwise (1024x1024)
__global__ __launch_bounds__(256)
void crpe_k(const float* __restrict__ R, __hip_bfloat16* __restrict__ Rb)
{
  const size_t t = ((size_t)blockIdx.x * 256 + threadIdx.x) * 8;
  const float4 f0 = ld4(R + t), f1 = ld4(R + t + 4);
  short8 s;
  s[0]=bfbits(f0.x); s[1]=bfbits(f0.y); s[2]=bfbits(f0.z); s[3]=bfbits(f0.w);
  s[4]=bfbits(f1.x); s[5]=bfbits(f1.y); s[6]=bfbits(f1.z); s[7]=bfbits(f1.w);
  *reinterpret_cast<short8*>((short*)Rb + t) = s;
}

// ---------------------------------------------------------------------------
// MFMA GEMM (m97 structure). MODE 2/3/4 epilogues; MODE 7 = merged KE+VE
// (Wt spans WtK|WtV 2048 rows; col<1024 -> KE layout, else VE layout).
// ---------------------------------------------------------------------------
template<int MODE>
__global__ __launch_bounds__(256)
void mgemm(const __hip_bfloat16* __restrict__ A,
           const __hip_bfloat16* __restrict__ Wt,
           const float* __restrict__ P0, const float* __restrict__ P1,
           const int* __restrict__ lp, const int* __restrict__ sp,
           __hip_bfloat16* __restrict__ Cb, __hip_bfloat16* __restrict__ Cb2,
           float* __restrict__ C)
{
  __shared__ __align__(16) short As[128 * 64];
  __shared__ __align__(16) short Bs[128 * 64];
  const int tid = threadIdx.x;
  const int w   = tid >> 6;
  const int l   = tid & 63;
  const int l15 = l & 15, lg = l >> 4;
  const int m0 = blockIdx.y * 128;
  const int n0 = blockIdx.x * 128;
  const int wr = (w >> 1) * 64;
  const int wc = (w & 1) * 64;

  f32x4 acc[4][4];
  #pragma unroll
  for (int mi = 0; mi < 4; ++mi)
    #pragma unroll
    for (int ni = 0; ni < 4; ++ni) acc[mi][ni] = (f32x4){0.f, 0.f, 0.f, 0.f};

  const int srow = (l >> 3);
  const int scol = (l & 7) * 8;

  for (int k0 = 0; k0 < 1024; k0 += 64) {
    if (k0) __syncthreads();
    #pragma unroll
    for (int q = 0; q < 4; ++q) {
      const int seg = w * 32 + q * 8;
      const int ra = m0 + seg + srow;
      size_t aoff;
      if (MODE == 4)
        aoff = ((size_t)(ra >> 9) * 1024 + 512 + (ra & 511)) * 1024;
      else
        aoff = (size_t)ra * 1024;
      gload16((const short*)A + aoff + k0 + scol, &As[seg * 64]);
      const int rb = n0 + seg + srow;
      gload16((const short*)Wt + (size_t)rb * 1024 + k0 + scol, &Bs[seg * 64]);
    }
    __syncthreads();
    #pragma unroll
    for (int kk = 0; kk < 2; ++kk) {
      short8 a[4], bf[4];
      #pragma unroll
      for (int mi = 0; mi < 4; ++mi)
        a[mi] = *reinterpret_cast<const short8*>(
            &As[(wr + mi * 16 + l15) * 64 + kk * 32 + lg * 8]);
      #pragma unroll
      for (int ni = 0; ni < 4; ++ni)
        bf[ni] = *reinterpret_cast<const short8*>(
            &Bs[(wc + ni * 16 + l15) * 64 + kk * 32 + lg * 8]);
      #pragma unroll
      for (int mi = 0; mi < 4; ++mi)
        #pragma unroll
        for (int ni = 0; ni < 4; ++ni)
          acc[mi][ni] = __builtin_amdgcn_mfma_f32_16x16x32_bf16(
              a[mi], bf[ni], acc[mi][ni], 0, 0, 0);
    }
  }

  #pragma unroll
  for (int mi = 0; mi < 4; ++mi) {
    const int rbase = m0 + wr + mi * 16 + lg * 4;
    #pragma unroll
    for (int ni = 0; ni < 4; ++ni) {
      const int col = n0 + wc + ni * 16 + l15;
      #pragma unroll
      for (int rr = 0; rr < 4; ++rr) {
        const int row = rbase + rr;
        const float val = acc[mi][ni][rr];
        if (MODE == 3) {
          Cb[(size_t)row * 1024 + col] = __float2bfloat16(val);
        } else if (MODE == 4) {
          const int nh = col >> 6, dd = col & 63;
          const int i = row >> 3, bb = row & 7;
          const size_t o = (((size_t)(bb * 16 + nh) * 512) + i) * 64 + dd;
          Cb [o] = __float2bfloat16(val + P0[col]);
          Cb2[o] = __float2bfloat16(val + P1[col]);
        } else if (MODE == 7) {
          const int cc = col & 1023;
          const int nh = cc >> 6, dd = cc & 63;
          const int j = row >> 3, bb = row & 7;
          __hip_bfloat16* dst = (col < 1024) ? Cb : Cb2;
          dst[(((size_t)(bb * 16 + nh) * 1024) + j) * 64 + dd] =
              __float2bfloat16(val);
        } else if (MODE == 2) {
          const float o = val + P0[col];
          C[(size_t)row * 1024 + col] = o;
          const int b2 = row >> 9, s2 = row & 511;
          C[OUT_OFF +
            (((size_t)lp[0] * 8 + b2) * 1536 + 512 + (size_t)sp[0] * 512 + s2) *
                1024 + col] = o;
        }
      }
    }
  }
}

// ---------------------------------------------------------------------------
// VE[b][n][j][d] -> Vt[b][n][d][j]  (bf16). grid (16 j-tiles, 128 bn).
// ---------------------------------------------------------------------------
__global__ __launch_bounds__(256)
void tr_k(const __hip_bfloat16* __restrict__ VE, __hip_bfloat16* __restrict__ Vt)
{
  __shared__ short T[64][72];
  const int t = threadIdx.x;
  const int j0 = blockIdx.x * 64;
  const int bn = blockIdx.y;
  #pragma unroll
  for (int it = 0; it < 2; ++it) {
    const int jl = (t >> 3) + it * 32;
    const int d8 = (t & 7) * 8;
    *reinterpret_cast<short8*>(&T[jl][d8]) =
        *reinterpret_cast<const short8*>(
            (const short*)VE + ((size_t)bn * 1024 + j0 + jl) * 64 + d8);
  }
  __syncthreads();
  #pragma unroll
  for (int it = 0; it < 2; ++it) {
    const int dl = (t >> 3) + it * 32;
    const int j8 = (t & 7) * 8;
    short8 s;
    #pragma unroll
    for (int e = 0; e < 8; ++e) s[e] = T[j8 + e][dl];
    *reinterpret_cast<short8*>(
        (short*)Vt + ((size_t)bn * 64 + dl) * 1024 + j0 + j8) = s;
  }
}

// ---------------------------------------------------------------------------
// Fused MFMA attention (r16 structure) + woven new_mem copy, burst SPLIT
// across both half-tiles (1 nt-store + 1 nt-load per drain instead of 4 ops
// at half-0): halves the per-drain VMEM burst that each vmcnt(0) must
// retire. Same addresses/op count as r21; epilogue stores chunk 31.
// Grid: 256 blocks = 8 b x 32 i-tiles, b = bid&7 (XCD-pinned).
// ---------------------------------------------------------------------------
__global__ __launch_bounds__(512, 1)
void attn2(const __hip_bfloat16* __restrict__ QU, const __hip_bfloat16* __restrict__ QV,
           const __hip_bfloat16* __restrict__ KE, const __hip_bfloat16* __restrict__ Vt,
           const __hip_bfloat16* __restrict__ KR, __hip_bfloat16* __restrict__ Ob,
           const float* __restrict__ Msrc, float* __restrict__ Mdst, int doCopy)
{
  __shared__ __align__(16) short stg[49152];    // 8 waves x (KE 2048 + KR 4096)
  __shared__ float Lbuf[16*16*33];              // [n][i][33], 32 j cols
  __shared__ __hip_bfloat16 Abuf[16*16*40];     // [n][i][40] att bf16

  const int bid = blockIdx.x;          // 0..255
  const int b   = bid & 7;             // XCD-pinned batch
  const int i0  = (bid >> 3) * 16;
  const int tid = threadIdx.x;
  const int w   = tid >> 6;
  const int l   = tid & 63;
  const int l15 = l & 15;
  const int lg  = l >> 4;

  short* keW = stg + w * 6144;         // 2048 shorts = 4KB KE slice
  short* krW = keW + 2048;             // 4096 shorts = 8KB KR band

  const short* KEs = (const short*)KE;
  const short* KRs = (const short*)KR;

  short8 qu[2][2], qv[2][2];
  #pragma unroll
  for (int hh = 0; hh < 2; ++hh) {
    const int h = 2*w + hh;
    const size_t qb = (((size_t)(b*16 + h) * 512) + i0 + l15) * 64 + lg*8;
    #pragma unroll
    for (int kf = 0; kf < 2; ++kf) {
      qu[hh][kf] = *reinterpret_cast<const short8*>(QU + qb + kf*32);
      qv[hh][kf] = *reinterpret_cast<const short8*>(QV + qb + kf*32);
    }
  }

  f32x4 oacc[2][4];
  #pragma unroll
  for (int hh = 0; hh < 2; ++hh)
    #pragma unroll
    for (int nf = 0; nf < 4; ++nf) oacc[hh][nf] = (f32x4){0.f,0.f,0.f,0.f};

  // pipelined copy state
  f32x4 c0 = {0,0,0,0}, c1 = {0,0,0,0};

  // stage KE rows [j0, j0+16) for both heads + KR band rows [pb, pb+32).
  auto stage = [&](int j0) {
    const int pb = 496 - i0 + j0;
    #pragma unroll
    for (int q = 0; q < 4; ++q) {
      const int R  = q*8 + (l >> 3);      // 0..31: hh = R>>4, jl = R&15
      const int hh = R >> 4, jl = R & 15;
      const int c  = (l & 7) ^ (R & 7);   // swizzled 16B-chunk of the row
      gload16(KEs + (((size_t)(b*16 + 2*w + hh) * 1024) + j0 + jl) * 64 + c * 8,
              keW + q * 512);
    }
    #pragma unroll
    for (int q = 0; q < 8; ++q) {
      const int r = q*4 + (l >> 4);       // band row 0..31
      const int c = (l & 15) ^ (r & 15);  // swizzled 16B-chunk of the row
      gload16(KRs + ((size_t)(pb + r)) * 1024 + w * 128 + c * 8,
              krW + q * 512);
    }
  };

  stage(0);   // prologue: tile 0 in flight

  for (int pr = 0; pr < 32; ++pr) {
    const int j0e = pr * 32;
    short8 vb[2][4];

    #pragma unroll
    for (int half = 0; half < 2; ++half) {
      const int j0 = j0e + half * 16;

      asm volatile("s_waitcnt vmcnt(0)" ::: "memory");
      __builtin_amdgcn_sched_barrier(0);

      // ---- woven nt copy: 1 store + 1 load per drain (split burst) ----
      if (doCopy) {
        const size_t prev = (((size_t)((pr - 1) * 256 + bid)) * 512 + tid) * 8;
        const size_t cur  = (((size_t)(pr * 256 + bid)) * 512 + tid) * 8;
        if (half == 0) {
          if (pr > 0 && prev + 8 <= (size_t)NM_ELEMS) stnt(Mdst + prev, c0);
          if (cur + 8 <= (size_t)NM_ELEMS)            c0 = ldnt(Msrc + cur);
        } else {
          if (pr > 0 && prev + 8 <= (size_t)NM_ELEMS) stnt(Mdst + prev + 4, c1);
          if (cur + 8 <= (size_t)NM_ELEMS)            c1 = ldnt(Msrc + cur + 4);
        }
      }

      // ---- LDS -> frag registers (swizzled read addresses) ----
      short8 kef[2][2], krf[2][2][2];
      #pragma unroll
      for (int hh = 0; hh < 2; ++hh)
        #pragma unroll
        for (int kf = 0; kf < 2; ++kf) {
          const int rowE = hh*16 + l15;
          const int kcE  = (kf*4 + lg) ^ (rowE & 7);
          kef[hh][kf] = *reinterpret_cast<const short8*>(
              keW + rowE*64 + kcE*8);
          #pragma unroll
          for (int nf = 0; nf < 2; ++nf) {
            const int rowR = nf*16 + l15;
            const int kcR  = (hh*8 + kf*4 + lg) ^ (rowR & 15);
            krf[hh][nf][kf] = *reinterpret_cast<const short8*>(
                krW + rowR*128 + kcR*8);
          }
        }

      // ---- QK + T MFMAs ----
      __builtin_amdgcn_s_setprio(1);
      f32x4 ac[2], tf[2][2];
      #pragma unroll
      for (int hh = 0; hh < 2; ++hh) {
        ac[hh]    = (f32x4){0,0,0,0};
        tf[hh][0] = (f32x4){0,0,0,0};
        tf[hh][1] = (f32x4){0,0,0,0};
        #pragma unroll
        for (int kf = 0; kf < 2; ++kf) {
          ac[hh] = __builtin_amdgcn_mfma_f32_16x16x32_bf16(
              qu[hh][kf], kef[hh][kf], ac[hh], 0, 0, 0);
          #pragma unroll
          for (int nf = 0; nf < 2; ++nf)
            tf[hh][nf] = __builtin_amdgcn_mfma_f32_16x16x32_bf16(
                qv[hh][kf], krf[hh][nf][kf], tf[hh][nf], 0, 0, 0);
        }
      }
      __builtin_amdgcn_s_setprio(0);

      // ---- LDS reads drained -> re-stage next half-tile now ----
      asm volatile("s_waitcnt lgkmcnt(0)" ::: "memory");
      __builtin_amdgcn_sched_barrier(0);
      stage(j0 + 16);
      if (half == 0) {
        #pragma unroll
        for (int hh = 0; hh < 2; ++hh) {
          const int h = 2*w + hh;
          #pragma unroll
          for (int nf = 0; nf < 4; ++nf)
            vb[hh][nf] = *reinterpret_cast<const short8*>(
              Vt + (((size_t)(b*16 + h) * 64) + nf*16 + l15) * 1024 + j0e + lg*8);
        }
      }

      // ---- gather bd + logits to Lbuf cols [half*16, half*16+16) ----
      #pragma unroll
      for (int hh = 0; hh < 2; ++hh) {
        const int h = 2*w + hh;
        #pragma unroll
        for (int r = 0; r < 4; ++r) {
          const int ip  = lg*4 + r;
          const int idx = 15 - ip + l15;        // 0..30
          const int nf  = idx >> 4;
          const int Ls  = lg*16 + (idx & 15);
          const float v0 = __shfl(tf[hh][0][r], Ls, 64);
          const float v1 = __shfl(tf[hh][1][r], Ls, 64);
          const float bd = nf ? v1 : v0;
          Lbuf[(h*16 + ip)*33 + half*16 + l15] = 0.125f * (ac[hh][r] + bd);
        }
      }
    }
    barrier_nodrain();

    // ---- softmax over 16 heads: 512 threads, one (i,j) each ----
    {
      const int si = tid >> 5, sj = tid & 31;
      float vals[16];
      float m = -3.0e38f;
      #pragma unroll
      for (int n = 0; n < 16; ++n) {
        vals[n] = Lbuf[(n*16 + si)*33 + sj];
        m = fmaxf(m, vals[n]);
      }
      float s = 0.f;
      #pragma unroll
      for (int n = 0; n < 16; ++n) { vals[n] = __expf(vals[n] - m); s += vals[n]; }
      const float rinv = 1.0f / s;
      #pragma unroll
      for (int n = 0; n < 16; ++n)
        Abuf[(n*16 + si)*40 + sj] = __float2bfloat16(vals[n] * rinv);
    }
    barrier_nodrain();

    // ---- PV (k=32 over both halves' j) ----
    __builtin_amdgcn_s_setprio(1);
    #pragma unroll
    for (int hh = 0; hh < 2; ++hh) {
      const int h = 2*w + hh;
      const short8 af = *reinterpret_cast<const short8*>(
          &Abuf[(h*16 + l15)*40 + lg*8]);
      #pragma unroll
      for (int nf = 0; nf < 4; ++nf)
        oacc[hh][nf] = __builtin_amdgcn_mfma_f32_16x16x32_bf16(
            af, vb[hh][nf], oacc[hh][nf], 0, 0, 0);
    }
    __builtin_amdgcn_s_setprio(0);
  }

  // copy epilogue: store chunk(31)
  if (doCopy) {
    const size_t last = (((size_t)(31 * 256 + bid)) * 512 + tid) * 8;
    if (last + 8 <= (size_t)NM_ELEMS) {
      stnt(Mdst + last, c0);
      stnt(Mdst + last + 4, c1);
    }
  }

  // store bf16 O rows r = i*8+b, cols h*64 + nf*16 + l15
  #pragma unroll
  for (int hh = 0; hh < 2; ++hh) {
    const int h = 2*w + hh;
    #pragma unroll
    for (int nf = 0; nf < 4; ++nf)
      #pragma unroll
      for (int r = 0; r < 4; ++r) {
        const int i = i0 + lg*4 + r;
        Ob[((size_t)(i*8 + b)) * 1024 + h*64 + nf*16 + l15] =
            __float2bfloat16(oacc[hh][nf][r]);
      }
  }
}

// ---------------------------------------------------------------------------
extern "C" void kernel_launch(void* const* d_in, const int* in_sizes, int n_in,
                              void* d_out, int out_size, void* d_ws, size_t ws_size,
                              hipStream_t stream)
{
  const float* x   = (const float*)d_in[0];
  const float* rpe = (const float*)d_in[1];
  const float* mem = (const float*)d_in[3];
  const float* Wq  = (const float*)d_in[4];
  const float* Wke = (const float*)d_in[5];
  const float* Wv  = (const float*)d_in[6];
  const float* Wkr = (const float*)d_in[7];
  const float* u   = (const float*)d_in[8];
  const float* v   = (const float*)d_in[9];
  const float* Wo  = (const float*)d_in[10];
  const float* bo  = (const float*)d_in[11];
  const int* lp    = (const int*)d_in[12];
  const int* sp    = (const int*)d_in[13];

  float* out = (float*)d_out;
  float* nm  = out + OUT_OFF;

  // ws layout (float offsets). Base 32.5 MB; if ws is large enough, KEb/Vtb
  // also live in ws (66.1 MB total) so attn2 can write new_mem concurrently.
  float* ws = (float*)d_ws;
  __hip_bfloat16* QUb = (__hip_bfloat16*)(ws);             // [8][16][512][64]
  __hip_bfloat16* QVb = (__hip_bfloat16*)(ws + 2097152);
  __hip_bfloat16* KRb = (__hip_bfloat16*)(ws + 4194304);   // [1536][1024]
  __hip_bfloat16* Ob  = (__hip_bfloat16*)(ws + 4980736);   // [4096][1024]
  __hip_bfloat16* Rb  = (__hip_bfloat16*)(ws + 7077888);   // [1024][1024]
  __hip_bfloat16* WtO = (__hip_bfloat16*)(ws + 7602176);   // [1024][1024]

  const bool big = ws_size >= (size_t)16515072 * 4;        // 66.06 MB
  // nm region scratch (dead before the copy)
  __hip_bfloat16* Kvx = (__hip_bfloat16*)(nm);              // [8192][1024]
  __hip_bfloat16* VEb = (__hip_bfloat16*)(nm + 8388608);
  __hip_bfloat16* WtQ = (__hip_bfloat16*)(nm + 16777216);
  __hip_bfloat16* WtK = (__hip_bfloat16*)(nm + 17301504);  // contiguous with
  __hip_bfloat16* WtV = (__hip_bfloat16*)(nm + 17825792);  //   WtK (2048 rows)
  __hip_bfloat16* WtR = (__hip_bfloat16*)(nm + 18350080);
  // KEb/Vtb: ws when big (attn2 inputs safe from the woven copy), else nm
  __hip_bfloat16* KEb = big ? (__hip_bfloat16*)(ws + 8126464)
                            : (__hip_bfloat16*)(nm + 4194304);
  __hip_bfloat16* Vtb = big ? (__hip_bfloat16*)(ws + 12320768)
                            : (__hip_bfloat16*)(nm + 12582912);

  dim3 blk(256);
  // zero KR pad rows 1024..1535 (rel_shift masking)
  hipMemsetAsync((void*)(KRb + (size_t)1024*1024), 0, (size_t)512*1024*2, stream);

  cw_k <<<dim3(16,16,5), blk, 0, stream>>>(Wq, Wke, Wv, Wkr, Wo,
                                           WtQ, WtK, WtV, WtR, WtO);
  ckvx_k<<<4096, blk, 0, stream>>>(x, mem, lp, sp, Kvx);
  crpe_k<<<512,  blk, 0, stream>>>(rpe, Rb);

  mgemm<3><<<dim3(8, 8),  blk, 0, stream>>>(Rb,  WtR, nullptr, nullptr, lp, sp, KRb, nullptr, nullptr);
  mgemm<4><<<dim3(8, 32), blk, 0, stream>>>(Kvx, WtQ, u, v,             lp, sp, QUb, QVb,     nullptr);
  // merged KE+VE: Wt spans WtK|WtV (2048 rows), N=2048
  mgemm<7><<<dim3(16, 64), blk, 0, stream>>>(Kvx, WtK, nullptr, nullptr, lp, sp, KEb, VEb, nullptr);

  tr_k<<<dim3(16, 128), blk, 0, stream>>>(VEb, Vtb);

  attn2<<<dim3(256), dim3(512), 0, stream>>>(QUb, QVb, KEb, Vtb, KRb, Ob,
                                             mem, nm, big ? 1 : 0);

  if (!big)
    hipMemcpyAsync(nm, mem, (size_t)NM_ELEMS * 4ull, hipMemcpyDeviceToDevice, stream);

  mgemm<2><<<dim3(8, 32), blk, 0, stream>>>(Ob, WtO, bo, nullptr, lp, sp, nullptr, nullptr, out);
}

// Round 23
// 337.258 us; speedup vs baseline: 1.0614x; 1.0614x over previous
//
#include <hip/hip_runtime.h>
#include <hip/hip_bf16.h>

// S=512, M=512, B=8, NH=16, HD=64, H=1024, K=1024, LAYERS=2, TOTAL_LEN=1536
#define OUT_OFF 4194304      // B*S*H floats (part-1 of d_out)
#define NM_ELEMS 25165824    // 2*8*1536*1024 floats (part-2: new_mem)

typedef __attribute__((ext_vector_type(8))) short short8;
typedef __attribute__((ext_vector_type(4))) float f32x4;

static __device__ __forceinline__ float4 ld4(const float* p) {
  return *reinterpret_cast<const float4*>(p);
}
static __device__ __forceinline__ void st4(float* p, float4 v) {
  *reinterpret_cast<float4*>(p) = v;
}
// non-temporal 16B copy ops (nt cache policy)
static __device__ __forceinline__ f32x4 ldnt(const float* p) {
  return __builtin_nontemporal_load(reinterpret_cast<const f32x4*>(p));
}
static __device__ __forceinline__ void stnt(float* p, f32x4 v) {
  __builtin_nontemporal_store(v, reinterpret_cast<f32x4*>(p));
}
static __device__ __forceinline__ short bfbits(float f) {
  __hip_bfloat16 h = __float2bfloat16(f);
  return *reinterpret_cast<short*>(&h);
}
// async global->LDS, 16B per lane; lds base must be wave-uniform.
static __device__ __forceinline__ void gload16(const void* g, void* l) {
  __builtin_amdgcn_global_load_lds(
      (const __attribute__((address_space(1))) void*)g,
      (__attribute__((address_space(3))) void*)l, 16, 0, 0);
}
// Barrier ordering LDS only (lgkm); keeps VMEM prefetches in flight.
static __device__ __forceinline__ void barrier_nodrain() {
  asm volatile("s_waitcnt lgkmcnt(0)" ::: "memory");
  __builtin_amdgcn_sched_barrier(0);
  __builtin_amdgcn_s_barrier();
  __builtin_amdgcn_sched_barrier(0);
}

// ---------------------------------------------------------------------------
// Pre-pass 1: weight transpose+convert. Wt[n][k] = bf16(W[k][n]), 1024x1024.
// ---------------------------------------------------------------------------
__global__ __launch_bounds__(256)
void cw_k(const float* __restrict__ W0, const float* __restrict__ W1,
          const float* __restrict__ W2, const float* __restrict__ W3,
          const float* __restrict__ W4,
          __hip_bfloat16* __restrict__ T0, __hip_bfloat16* __restrict__ T1,
          __hip_bfloat16* __restrict__ T2, __hip_bfloat16* __restrict__ T3,
          __hip_bfloat16* __restrict__ T4)
{
  const float* W; __hip_bfloat16* T;
  switch (blockIdx.z) {
    case 0: W = W0; T = T0; break;
    case 1: W = W1; T = T1; break;
    case 2: W = W2; T = T2; break;
    case 3: W = W3; T = T3; break;
    default: W = W4; T = T4; break;
  }
  __shared__ short S[64][72];
  const int t = threadIdx.x;
  const int n0 = blockIdx.x * 64, k0 = blockIdx.y * 64;
  #pragma unroll
  for (int it = 0; it < 2; ++it) {
    const int kl = (t >> 3) + it * 32;
    const int n8 = (t & 7) * 8;
    const float* src = W + (size_t)(k0 + kl) * 1024 + n0 + n8;
    const float4 f0 = ld4(src), f1 = ld4(src + 4);
    short8 s;
    s[0]=bfbits(f0.x); s[1]=bfbits(f0.y); s[2]=bfbits(f0.z); s[3]=bfbits(f0.w);
    s[4]=bfbits(f1.x); s[5]=bfbits(f1.y); s[6]=bfbits(f1.z); s[7]=bfbits(f1.w);
    *reinterpret_cast<short8*>(&S[kl][n8]) = s;
  }
  __syncthreads();
  #pragma unroll
  for (int it = 0; it < 2; ++it) {
    const int nl = (t >> 3) + it * 32;
    const int k8 = (t & 7) * 8;
    short8 s;
    #pragma unroll
    for (int e = 0; e < 8; ++e) s[e] = S[k8 + e][nl];
    *reinterpret_cast<short8*>((short*)T + (size_t)(n0 + nl) * 1024 + k0 + k8) = s;
  }
}

// ---------------------------------------------------------------------------
// Pre-pass 2: Kvx[r][k] bf16, r = b*1024 + j gathered from mem slice / x.
// ---------------------------------------------------------------------------
__global__ __launch_bounds__(256)
void ckvx_k(const float* __restrict__ x, const float* __restrict__ mem,
            const int* __restrict__ lp, const int* __restrict__ sp,
            __hip_bfloat16* __restrict__ Kvx)
{
  const size_t t = (size_t)blockIdx.x * 256 + threadIdx.x;
  const int r = (int)(t >> 7);
  const int c = (int)(t & 127) * 8;
  const int b = r >> 10, j = r & 1023;
  const float* src = (j < 512)
    ? mem + (((size_t)lp[0] * 8 + b) * 1536 + (size_t)sp[0] * 512 + j) * 1024 + c
    : x + ((size_t)b * 512 + (j - 512)) * 1024 + c;
  const float4 f0 = ld4(src), f1 = ld4(src + 4);
  short8 s;
  s[0]=bfbits(f0.x); s[1]=bfbits(f0.y); s[2]=bfbits(f0.z); s[3]=bfbits(f0.w);
  s[4]=bfbits(f1.x); s[5]=bfbits(f1.y); s[6]=bfbits(f1.z); s[7]=bfbits(f1.w);
  *reinterpret_cast<short8*>((short*)Kvx + (size_t)r * 1024 + c) = s;
}

// Pre-pass 3: rpe fp32 -> bf16 elementwise (1024x1024)
__global__ __launch_bounds__(256)
void crpe_k(const float* __restrict__ R, __hip_bfloat16* __restrict__ Rb)
{
  const size_t t = ((size_t)blockIdx.x * 256 + threadIdx.x) * 8;
  const float4 f0 = ld4(R + t), f1 = ld4(R + t + 4);
  short8 s;
  s[0]=bfbits(f0.x); s[1]=bfbits(f0.y); s[2]=bfbits(f0.z); s[3]=bfbits(f0.w);
  s[4]=bfbits(f1.x); s[5]=bfbits(f1.y); s[6]=bfbits(f1.z); s[7]=bfbits(f1.w);
  *reinterpret_cast<short8*>((short*)Rb + t) = s;
}

// ---------------------------------------------------------------------------
// MFMA GEMM (m97 structure). MODE 2/3/4 epilogues; MODE 7 = merged KE+VE
// (Wt spans WtK|WtV 2048 rows; col<1024 -> KE layout, else VE layout).
// ---------------------------------------------------------------------------
template<int MODE>
__global__ __launch_bounds__(256)
void mgemm(const __hip_bfloat16* __restrict__ A,
           const __hip_bfloat16* __restrict__ Wt,
           const float* __restrict__ P0, const float* __restrict__ P1,
           const int* __restrict__ lp, const int* __restrict__ sp,
           __hip_bfloat16* __restrict__ Cb, __hip_bfloat16* __restrict__ Cb2,
           float* __restrict__ C)
{
  __shared__ __align__(16) short As[128 * 64];
  __shared__ __align__(16) short Bs[128 * 64];
  const int tid = threadIdx.x;
  const int w   = tid >> 6;
  const int l   = tid & 63;
  const int l15 = l & 15, lg = l >> 4;
  const int m0 = blockIdx.y * 128;
  const int n0 = blockIdx.x * 128;
  const int wr = (w >> 1) * 64;
  const int wc = (w & 1) * 64;

  f32x4 acc[4][4];
  #pragma unroll
  for (int mi = 0; mi < 4; ++mi)
    #pragma unroll
    for (int ni = 0; ni < 4; ++ni) acc[mi][ni] = (f32x4){0.f, 0.f, 0.f, 0.f};

  const int srow = (l >> 3);
  const int scol = (l & 7) * 8;

  for (int k0 = 0; k0 < 1024; k0 += 64) {
    if (k0) __syncthreads();
    #pragma unroll
    for (int q = 0; q < 4; ++q) {
      const int seg = w * 32 + q * 8;
      const int ra = m0 + seg + srow;
      size_t aoff;
      if (MODE == 4)
        aoff = ((size_t)(ra >> 9) * 1024 + 512 + (ra & 511)) * 1024;
      else
        aoff = (size_t)ra * 1024;
      gload16((const short*)A + aoff + k0 + scol, &As[seg * 64]);
      const int rb = n0 + seg + srow;
      gload16((const short*)Wt + (size_t)rb * 1024 + k0 + scol, &Bs[seg * 64]);
    }
    __syncthreads();
    #pragma unroll
    for (int kk = 0; kk < 2; ++kk) {
      short8 a[4], bf[4];
      #pragma unroll
      for (int mi = 0; mi < 4; ++mi)
        a[mi] = *reinterpret_cast<const short8*>(
            &As[(wr + mi * 16 + l15) * 64 + kk * 32 + lg * 8]);
      #pragma unroll
      for (int ni = 0; ni < 4; ++ni)
        bf[ni] = *reinterpret_cast<const short8*>(
            &Bs[(wc + ni * 16 + l15) * 64 + kk * 32 + lg * 8]);
      #pragma unroll
      for (int mi = 0; mi < 4; ++mi)
        #pragma unroll
        for (int ni = 0; ni < 4; ++ni)
          acc[mi][ni] = __builtin_amdgcn_mfma_f32_16x16x32_bf16(
              a[mi], bf[ni], acc[mi][ni], 0, 0, 0);
    }
  }

  #pragma unroll
  for (int mi = 0; mi < 4; ++mi) {
    const int rbase = m0 + wr + mi * 16 + lg * 4;
    #pragma unroll
    for (int ni = 0; ni < 4; ++ni) {
      const int col = n0 + wc + ni * 16 + l15;
      #pragma unroll
      for (int rr = 0; rr < 4; ++rr) {
        const int row = rbase + rr;
        const float val = acc[mi][ni][rr];
        if (MODE == 3) {
          Cb[(size_t)row * 1024 + col] = __float2bfloat16(val);
        } else if (MODE == 4) {
          const int nh = col >> 6, dd = col & 63;
          const int i = row >> 3, bb = row & 7;
          const size_t o = (((size_t)(bb * 16 + nh) * 512) + i) * 64 + dd;
          Cb [o] = __float2bfloat16(val + P0[col]);
          Cb2[o] = __float2bfloat16(val + P1[col]);
        } else if (MODE == 7) {
          const int cc = col & 1023;
          const int nh = cc >> 6, dd = cc & 63;
          const int j = row >> 3, bb = row & 7;
          __hip_bfloat16* dst = (col < 1024) ? Cb : Cb2;
          dst[(((size_t)(bb * 16 + nh) * 1024) + j) * 64 + dd] =
              __float2bfloat16(val);
        } else if (MODE == 2) {
          const float o = val + P0[col];
          C[(size_t)row * 1024 + col] = o;
          const int b2 = row >> 9, s2 = row & 511;
          C[OUT_OFF +
            (((size_t)lp[0] * 8 + b2) * 1536 + 512 + (size_t)sp[0] * 512 + s2) *
                1024 + col] = o;
        }
      }
    }
  }
}

// ---------------------------------------------------------------------------
// VE[b][n][j][d] -> Vt[b][n][d][j]  (bf16). grid (16 j-tiles, 128 bn).
// ---------------------------------------------------------------------------
__global__ __launch_bounds__(256)
void tr_k(const __hip_bfloat16* __restrict__ VE, __hip_bfloat16* __restrict__ Vt)
{
  __shared__ short T[64][72];
  const int t = threadIdx.x;
  const int j0 = blockIdx.x * 64;
  const int bn = blockIdx.y;
  #pragma unroll
  for (int it = 0; it < 2; ++it) {
    const int jl = (t >> 3) + it * 32;
    const int d8 = (t & 7) * 8;
    *reinterpret_cast<short8*>(&T[jl][d8]) =
        *reinterpret_cast<const short8*>(
            (const short*)VE + ((size_t)bn * 1024 + j0 + jl) * 64 + d8);
  }
  __syncthreads();
  #pragma unroll
  for (int it = 0; it < 2; ++it) {
    const int dl = (t >> 3) + it * 32;
    const int j8 = (t & 7) * 8;
    short8 s;
    #pragma unroll
    for (int e = 0; e < 8; ++e) s[e] = T[j8 + e][dl];
    *reinterpret_cast<short8*>(
        (short*)Vt + ((size_t)bn * 64 + dl) * 1024 + j0 + j8) = s;
  }
}

// ---------------------------------------------------------------------------
// Fused MFMA attention (session best, r21): r16 2-phase structure + woven
// non-temporal new_mem copy (contiguous 32B/thread burst at half-0 drain;
// split bursts regressed via partial-line write amplification, r22).
// Grid: 256 blocks = 8 b x 32 i-tiles, b = bid&7 (XCD-pinned).
// ---------------------------------------------------------------------------
__global__ __launch_bounds__(512, 1)
void attn2(const __hip_bfloat16* __restrict__ QU, const __hip_bfloat16* __restrict__ QV,
           const __hip_bfloat16* __restrict__ KE, const __hip_bfloat16* __restrict__ Vt,
           const __hip_bfloat16* __restrict__ KR, __hip_bfloat16* __restrict__ Ob,
           const float* __restrict__ Msrc, float* __restrict__ Mdst, int doCopy)
{
  __shared__ __align__(16) short stg[49152];    // 8 waves x (KE 2048 + KR 4096)
  __shared__ float Lbuf[16*16*33];              // [n][i][33], 32 j cols
  __shared__ __hip_bfloat16 Abuf[16*16*40];     // [n][i][40] att bf16

  const int bid = blockIdx.x;          // 0..255
  const int b   = bid & 7;             // XCD-pinned batch
  const int i0  = (bid >> 3) * 16;
  const int tid = threadIdx.x;
  const int w   = tid >> 6;
  const int l   = tid & 63;
  const int l15 = l & 15;
  const int lg  = l >> 4;

  short* keW = stg + w * 6144;         // 2048 shorts = 4KB KE slice
  short* krW = keW + 2048;             // 4096 shorts = 8KB KR band

  const short* KEs = (const short*)KE;
  const short* KRs = (const short*)KR;

  short8 qu[2][2], qv[2][2];
  #pragma unroll
  for (int hh = 0; hh < 2; ++hh) {
    const int h = 2*w + hh;
    const size_t qb = (((size_t)(b*16 + h) * 512) + i0 + l15) * 64 + lg*8;
    #pragma unroll
    for (int kf = 0; kf < 2; ++kf) {
      qu[hh][kf] = *reinterpret_cast<const short8*>(QU + qb + kf*32);
      qv[hh][kf] = *reinterpret_cast<const short8*>(QV + qb + kf*32);
    }
  }

  f32x4 oacc[2][4];
  #pragma unroll
  for (int hh = 0; hh < 2; ++hh)
    #pragma unroll
    for (int nf = 0; nf < 4; ++nf) oacc[hh][nf] = (f32x4){0.f,0.f,0.f,0.f};

  // pipelined copy state
  f32x4 c0 = {0,0,0,0}, c1 = {0,0,0,0};

  // stage KE rows [j0, j0+16) for both heads + KR band rows [pb, pb+32).
  auto stage = [&](int j0) {
    const int pb = 496 - i0 + j0;
    #pragma unroll
    for (int q = 0; q < 4; ++q) {
      const int R  = q*8 + (l >> 3);      // 0..31: hh = R>>4, jl = R&15
      const int hh = R >> 4, jl = R & 15;
      const int c  = (l & 7) ^ (R & 7);   // swizzled 16B-chunk of the row
      gload16(KEs + (((size_t)(b*16 + 2*w + hh) * 1024) + j0 + jl) * 64 + c * 8,
              keW + q * 512);
    }
    #pragma unroll
    for (int q = 0; q < 8; ++q) {
      const int r = q*4 + (l >> 4);       // band row 0..31
      const int c = (l & 15) ^ (r & 15);  // swizzled 16B-chunk of the row
      gload16(KRs + ((size_t)(pb + r)) * 1024 + w * 128 + c * 8,
              krW + q * 512);
    }
  };

  stage(0);   // prologue: tile 0 in flight

  for (int pr = 0; pr < 32; ++pr) {
    const int j0e = pr * 32;
    short8 vb[2][4];

    #pragma unroll
    for (int half = 0; half < 2; ++half) {
      const int j0 = j0e + half * 16;

      asm volatile("s_waitcnt vmcnt(0)" ::: "memory");
      __builtin_amdgcn_sched_barrier(0);

      // ---- woven new_mem copy (non-temporal): store chunk(pr-1), load pr ----
      if (half == 0 && doCopy) {
        if (pr > 0) {
          const size_t prev = (((size_t)((pr - 1) * 256 + bid)) * 512 + tid) * 8;
          if (prev + 8 <= (size_t)NM_ELEMS) {
            stnt(Mdst + prev, c0);
            stnt(Mdst + prev + 4, c1);
          }
        }
        const size_t cur = (((size_t)(pr * 256 + bid)) * 512 + tid) * 8;
        if (cur + 8 <= (size_t)NM_ELEMS) {
          c0 = ldnt(Msrc + cur);
          c1 = ldnt(Msrc + cur + 4);
        }
      }

      // ---- LDS -> frag registers (swizzled read addresses) ----
      short8 kef[2][2], krf[2][2][2];
      #pragma unroll
      for (int hh = 0; hh < 2; ++hh)
        #pragma unroll
        for (int kf = 0; kf < 2; ++kf) {
          const int rowE = hh*16 + l15;
          const int kcE  = (kf*4 + lg) ^ (rowE & 7);
          kef[hh][kf] = *reinterpret_cast<const short8*>(
              keW + rowE*64 + kcE*8);
          #pragma unroll
          for (int nf = 0; nf < 2; ++nf) {
            const int rowR = nf*16 + l15;
            const int kcR  = (hh*8 + kf*4 + lg) ^ (rowR & 15);
            krf[hh][nf][kf] = *reinterpret_cast<const short8*>(
                krW + rowR*128 + kcR*8);
          }
        }

      // ---- QK + T MFMAs ----
      __builtin_amdgcn_s_setprio(1);
      f32x4 ac[2], tf[2][2];
      #pragma unroll
      for (int hh = 0; hh < 2; ++hh) {
        ac[hh]    = (f32x4){0,0,0,0};
        tf[hh][0] = (f32x4){0,0,0,0};
        tf[hh][1] = (f32x4){0,0,0,0};
        #pragma unroll
        for (int kf = 0; kf < 2; ++kf) {
          ac[hh] = __builtin_amdgcn_mfma_f32_16x16x32_bf16(
              qu[hh][kf], kef[hh][kf], ac[hh], 0, 0, 0);
          #pragma unroll
          for (int nf = 0; nf < 2; ++nf)
            tf[hh][nf] = __builtin_amdgcn_mfma_f32_16x16x32_bf16(
                qv[hh][kf], krf[hh][nf][kf], tf[hh][nf], 0, 0, 0);
        }
      }
      __builtin_amdgcn_s_setprio(0);

      // ---- LDS reads drained -> re-stage next half-tile now ----
      asm volatile("s_waitcnt lgkmcnt(0)" ::: "memory");
      __builtin_amdgcn_sched_barrier(0);
      stage(j0 + 16);
      if (half == 0) {
        #pragma unroll
        for (int hh = 0; hh < 2; ++hh) {
          const int h = 2*w + hh;
          #pragma unroll
          for (int nf = 0; nf < 4; ++nf)
            vb[hh][nf] = *reinterpret_cast<const short8*>(
              Vt + (((size_t)(b*16 + h) * 64) + nf*16 + l15) * 1024 + j0e + lg*8);
        }
      }

      // ---- gather bd + logits to Lbuf cols [half*16, half*16+16) ----
      #pragma unroll
      for (int hh = 0; hh < 2; ++hh) {
        const int h = 2*w + hh;
        #pragma unroll
        for (int r = 0; r < 4; ++r) {
          const int ip  = lg*4 + r;
          const int idx = 15 - ip + l15;        // 0..30
          const int nf  = idx >> 4;
          const int Ls  = lg*16 + (idx & 15);
          const float v0 = __shfl(tf[hh][0][r], Ls, 64);
          const float v1 = __shfl(tf[hh][1][r], Ls, 64);
          const float bd = nf ? v1 : v0;
          Lbuf[(h*16 + ip)*33 + half*16 + l15] = 0.125f * (ac[hh][r] + bd);
        }
      }
    }
    barrier_nodrain();

    // ---- softmax over 16 heads: 512 threads, one (i,j) each ----
    {
      const int si = tid >> 5, sj = tid & 31;
      float vals[16];
      float m = -3.0e38f;
      #pragma unroll
      for (int n = 0; n < 16; ++n) {
        vals[n] = Lbuf[(n*16 + si)*33 + sj];
        m = fmaxf(m, vals[n]);
      }
      float s = 0.f;
      #pragma unroll
      for (int n = 0; n < 16; ++n) { vals[n] = __expf(vals[n] - m); s += vals[n]; }
      const float rinv = 1.0f / s;
      #pragma unroll
      for (int n = 0; n < 16; ++n)
        Abuf[(n*16 + si)*40 + sj] = __float2bfloat16(vals[n] * rinv);
    }
    barrier_nodrain();

    // ---- PV (k=32 over both halves' j) ----
    __builtin_amdgcn_s_setprio(1);
    #pragma unroll
    for (int hh = 0; hh < 2; ++hh) {
      const int h = 2*w + hh;
      const short8 af = *reinterpret_cast<const short8*>(
          &Abuf[(h*16 + l15)*40 + lg*8]);
      #pragma unroll
      for (int nf = 0; nf < 4; ++nf)
        oacc[hh][nf] = __builtin_amdgcn_mfma_f32_16x16x32_bf16(
            af, vb[hh][nf], oacc[hh][nf], 0, 0, 0);
    }
    __builtin_amdgcn_s_setprio(0);
  }

  // copy epilogue: store chunk(31)
  if (doCopy) {
    const size_t last = (((size_t)(31 * 256 + bid)) * 512 + tid) * 8;
    if (last + 8 <= (size_t)NM_ELEMS) {
      stnt(Mdst + last, c0);
      stnt(Mdst + last + 4, c1);
    }
  }

  // store bf16 O rows r = i*8+b, cols h*64 + nf*16 + l15
  #pragma unroll
  for (int hh = 0; hh < 2; ++hh) {
    const int h = 2*w + hh;
    #pragma unroll
    for (int nf = 0; nf < 4; ++nf)
      #pragma unroll
      for (int r = 0; r < 4; ++r) {
        const int i = i0 + lg*4 + r;
        Ob[((size_t)(i*8 + b)) * 1024 + h*64 + nf*16 + l15] =
            __float2bfloat16(oacc[hh][nf][r]);
      }
  }
}

// ---------------------------------------------------------------------------
extern "C" void kernel_launch(void* const* d_in, const int* in_sizes, int n_in,
                              void* d_out, int out_size, void* d_ws, size_t ws_size,
                              hipStream_t stream)
{
  const float* x   = (const float*)d_in[0];
  const float* rpe = (const float*)d_in[1];
  const float* mem = (const float*)d_in[3];
  const float* Wq  = (const float*)d_in[4];
  const float* Wke = (const float*)d_in[5];
  const float* Wv  = (const float*)d_in[6];
  const float* Wkr = (const float*)d_in[7];
  const float* u   = (const float*)d_in[8];
  const float* v   = (const float*)d_in[9];
  const float* Wo  = (const float*)d_in[10];
  const float* bo  = (const float*)d_in[11];
  const int* lp    = (const int*)d_in[12];
  const int* sp    = (const int*)d_in[13];

  float* out = (float*)d_out;
  float* nm  = out + OUT_OFF;

  // ws layout (float offsets). Base 32.5 MB; if ws is large enough, KEb/Vtb
  // also live in ws (66.1 MB total) so attn2 can write new_mem concurrently.
  float* ws = (float*)d_ws;
  __hip_bfloat16* QUb = (__hip_bfloat16*)(ws);             // [8][16][512][64]
  __hip_bfloat16* QVb = (__hip_bfloat16*)(ws + 2097152);
  __hip_bfloat16* KRb = (__hip_bfloat16*)(ws + 4194304);   // [1536][1024]
  __hip_bfloat16* Ob  = (__hip_bfloat16*)(ws + 4980736);   // [4096][1024]
  __hip_bfloat16* Rb  = (__hip_bfloat16*)(ws + 7077888);   // [1024][1024]
  __hip_bfloat16* WtO = (__hip_bfloat16*)(ws + 7602176);   // [1024][1024]

  const bool big = ws_size >= (size_t)16515072 * 4;        // 66.06 MB
  // nm region scratch (dead before the copy)
  __hip_bfloat16* Kvx = (__hip_bfloat16*)(nm);              // [8192][1024]
  __hip_bfloat16* VEb = (__hip_bfloat16*)(nm + 8388608);
  __hip_bfloat16* WtQ = (__hip_bfloat16*)(nm + 16777216);
  __hip_bfloat16* WtK = (__hip_bfloat16*)(nm + 17301504);  // contiguous with
  __hip_bfloat16* WtV = (__hip_bfloat16*)(nm + 17825792);  //   WtK (2048 rows)
  __hip_bfloat16* WtR = (__hip_bfloat16*)(nm + 18350080);
  // KEb/Vtb: ws when big (attn2 inputs safe from the woven copy), else nm
  __hip_bfloat16* KEb = big ? (__hip_bfloat16*)(ws + 8126464)
                            : (__hip_bfloat16*)(nm + 4194304);
  __hip_bfloat16* Vtb = big ? (__hip_bfloat16*)(ws + 12320768)
                            : (__hip_bfloat16*)(nm + 12582912);

  dim3 blk(256);
  // zero KR pad rows 1024..1535 (rel_shift masking)
  hipMemsetAsync((void*)(KRb + (size_t)1024*1024), 0, (size_t)512*1024*2, stream);

  cw_k <<<dim3(16,16,5), blk, 0, stream>>>(Wq, Wke, Wv, Wkr, Wo,
                                           WtQ, WtK, WtV, WtR, WtO);
  ckvx_k<<<4096, blk, 0, stream>>>(x, mem, lp, sp, Kvx);
  crpe_k<<<512,  blk, 0, stream>>>(rpe, Rb);

  mgemm<3><<<dim3(8, 8),  blk, 0, stream>>>(Rb,  WtR, nullptr, nullptr, lp, sp, KRb, nullptr, nullptr);
  mgemm<4><<<dim3(8, 32), blk, 0, stream>>>(Kvx, WtQ, u, v,             lp, sp, QUb, QVb,     nullptr);
  // merged KE+VE: Wt spans WtK|WtV (2048 rows), N=2048
  mgemm<7><<<dim3(16, 64), blk, 0, stream>>>(Kvx, WtK, nullptr, nullptr, lp, sp, KEb, VEb, nullptr);

  tr_k<<<dim3(16, 128), blk, 0, stream>>>(VEb, Vtb);

  attn2<<<dim3(256), dim3(512), 0, stream>>>(QUb, QVb, KEb, Vtb, KRb, Ob,
                                             mem, nm, big ? 1 : 0);

  if (!big)
    hipMemcpyAsync(nm, mem, (size_t)NM_ELEMS * 4ull, hipMemcpyDeviceToDevice, stream);

  mgemm<2><<<dim3(8, 32), blk, 0, stream>>>(Ob, WtO, bo, nullptr, lp, sp, nullptr, nullptr, out);
}